// Round 1
// baseline (478.442 us; speedup 1.0000x reference)
//
#include <hip/hip_runtime.h>

#define S_LEN 2048
#define D_MODEL 1024
#define NH 16
#define DHEAD 64
#define BATCH 4

typedef _Float16 half8 __attribute__((ext_vector_type(8)));
typedef float floatx4 __attribute__((ext_vector_type(4)));

__device__ __forceinline__ unsigned short f2h(float f) {
    _Float16 h = (_Float16)f;
    return __builtin_bit_cast(unsigned short, h);
}

// ---------------- conversion: fp32 -> fp16 bits (elementwise, x4 vectorized) ----
__global__ __launch_bounds__(256) void convert_f2h_kernel(const float* __restrict__ in,
                                                          unsigned short* __restrict__ out,
                                                          int n4) {
    int i = blockIdx.x * 256 + threadIdx.x;
    if (i < n4) {
        float4 v = ((const float4*)in)[i];
        ushort4 o;
        o.x = f2h(v.x); o.y = f2h(v.y); o.z = f2h(v.z); o.w = f2h(v.w);
        ((ushort4*)out)[i] = o;
    }
}

// ---------------- W [K][N] fp32 -> Wt [N][K] fp16, LDS tile transpose ------------
__global__ __launch_bounds__(256) void transpose_w_kernel(const float* __restrict__ W,
                                                          unsigned short* __restrict__ Wt) {
    __shared__ float tile[32][33];
    int x = threadIdx.x;   // 0..31
    int y = threadIdx.y;   // 0..7
    int k0 = blockIdx.y * 32;
    int n0 = blockIdx.x * 32;
    for (int i = 0; i < 4; i++)
        tile[y + 8 * i][x] = W[(size_t)(k0 + y + 8 * i) * D_MODEL + n0 + x];
    __syncthreads();
    for (int i = 0; i < 4; i++)
        Wt[(size_t)(n0 + y + 8 * i) * D_MODEL + k0 + x] = f2h(tile[x][y + 8 * i]);
}

// ---------------- NT GEMM: C[M][N] = A[M][K] * Bt[N][K]^T ------------------------
// MODE 0: write fp16 to Q/K layout [b][h][s][dh]
// MODE 1: write fp16 to V  layout [b][h][dh][s]
// MODE 2: write fp32 to [M][N]
template<int MODE>
__global__ __launch_bounds__(256) void gemm_nt_kernel(const unsigned short* __restrict__ A,
                                                      const unsigned short* __restrict__ Bt,
                                                      void* __restrict__ Cout,
                                                      int M, int N, int K) {
    constexpr int LDA = 40;   // padded row stride (fp16 elems): 80B -> 2-way banks on frag reads
    __shared__ unsigned short As[128 * LDA];
    __shared__ unsigned short Bs[128 * LDA];
    const int tid  = threadIdx.x;
    const int wave = tid >> 6;
    const int lane = tid & 63;
    const int quad = lane >> 4;
    const int l16  = lane & 15;
    const int wm = (wave >> 1) * 64;   // wave sub-tile row offset
    const int wn = (wave & 1) * 64;    // wave sub-tile col offset
    const int tm = blockIdx.y * 128;
    const int tn = blockIdx.x * 128;

    floatx4 acc[4][4] = {};

    for (int k0 = 0; k0 < K; k0 += 32) {
        // stage A tile (128x32) and Bt tile (128x32); 16B chunks, 2 per thread each
        for (int i = 0; i < 2; i++) {
            int c   = tid + 256 * i;
            int row = c >> 2;
            int seg = c & 3;
            uint4 va = *(const uint4*)(&A [(size_t)(tm + row) * K + k0 + seg * 8]);
            *(uint4*)(&As[row * LDA + seg * 8]) = va;
            uint4 vb = *(const uint4*)(&Bt[(size_t)(tn + row) * K + k0 + seg * 8]);
            *(uint4*)(&Bs[row * LDA + seg * 8]) = vb;
        }
        __syncthreads();
        half8 af[4], bf[4];
        for (int mi = 0; mi < 4; mi++)
            af[mi] = *(const half8*)(&As[(wm + mi * 16 + l16) * LDA + quad * 8]);
        for (int ni = 0; ni < 4; ni++)
            bf[ni] = *(const half8*)(&Bs[(wn + ni * 16 + l16) * LDA + quad * 8]);
        for (int mi = 0; mi < 4; mi++)
            for (int ni = 0; ni < 4; ni++)
                acc[mi][ni] = __builtin_amdgcn_mfma_f32_16x16x32_f16(af[mi], bf[ni], acc[mi][ni], 0, 0, 0);
        __syncthreads();
    }

    for (int mi = 0; mi < 4; mi++) {
        for (int ni = 0; ni < 4; ni++) {
            for (int r = 0; r < 4; r++) {
                int row = tm + wm + mi * 16 + quad * 4 + r;   // m
                int col = tn + wn + ni * 16 + l16;            // n
                float v = acc[mi][ni][r];
                if (MODE == 2) {
                    ((float*)Cout)[(size_t)row * N + col] = v;
                } else {
                    int b = row >> 11, s = row & 2047;
                    int h = col >> 6,  dh = col & 63;
                    size_t idx;
                    if (MODE == 0) idx = ((size_t)(b * NH + h) * S_LEN + s) * DHEAD + dh;
                    else           idx = ((size_t)(b * NH + h) * DHEAD + dh) * S_LEN + s;
                    ((unsigned short*)Cout)[idx] = f2h(v);
                }
            }
        }
    }
}

// ---------------- Flash attention (causal), 64 q-rows per block ------------------
// Q,K: [b][h][s][dh] fp16 ; Vt: [b][h][dh][s] fp16 ; ctx out: [b][s][h*dh] fp16
__global__ __launch_bounds__(256) void attn_kernel(const unsigned short* __restrict__ Q,
                                                   const unsigned short* __restrict__ K,
                                                   const unsigned short* __restrict__ Vt,
                                                   unsigned short* __restrict__ ctx) {
    constexpr int LD = 72;   // padded row stride (144B) -> 2-way banks on frag reads
    __shared__ unsigned short Qs[64 * LD];
    __shared__ unsigned short Ks[64 * LD];
    __shared__ unsigned short Vs[64 * LD];
    __shared__ unsigned short Ps[4][16 * LD];
    const int tid  = threadIdx.x;
    const int wave = tid >> 6;
    const int lane = tid & 63;
    const int quad = lane >> 4;
    const int l16  = lane & 15;
    const int qt = blockIdx.x;   // q tile (64 rows)
    const int h  = blockIdx.y;
    const int b  = blockIdx.z;
    const size_t head = (size_t)(b * NH + h) * S_LEN * DHEAD;  // base for Q,K,Vt (all same size)

    // stage Q tile once
    for (int i = 0; i < 2; i++) {
        int c = tid + 256 * i;
        int row = c >> 3, seg = c & 7;
        uint4 v = *(const uint4*)(&Q[head + (size_t)(qt * 64 + row) * DHEAD + seg * 8]);
        *(uint4*)(&Qs[row * LD + seg * 8]) = v;
    }

    floatx4 acc_o[4] = {};
    float m_r[4], l_r[4];
    for (int r = 0; r < 4; r++) { m_r[r] = -3.0e38f; l_r[r] = 0.f; }

    for (int kt = 0; kt <= qt; kt++) {
        __syncthreads();   // prior-iter readers done before restaging (also covers Q staging)
        for (int i = 0; i < 2; i++) {
            int c = tid + 256 * i;
            int row = c >> 3, seg = c & 7;
            uint4 vk = *(const uint4*)(&K [head + (size_t)(kt * 64 + row) * DHEAD + seg * 8]);
            *(uint4*)(&Ks[row * LD + seg * 8]) = vk;
            uint4 vv = *(const uint4*)(&Vt[head + (size_t)row * S_LEN + kt * 64 + seg * 8]);
            *(uint4*)(&Vs[row * LD + seg * 8]) = vv;
        }
        __syncthreads();

        // S = Q K^T : wave handles 16 q-rows x 64 kk
        floatx4 sc[4] = {};
        for (int ks = 0; ks < 2; ks++) {
            half8 aq = *(const half8*)(&Qs[(wave * 16 + l16) * LD + ks * 32 + quad * 8]);
            for (int nb = 0; nb < 4; nb++) {
                half8 bk = *(const half8*)(&Ks[(nb * 16 + l16) * LD + ks * 32 + quad * 8]);
                sc[nb] = __builtin_amdgcn_mfma_f32_16x16x32_f16(aq, bk, sc[nb], 0, 0, 0);
            }
        }

        // online softmax (rows = quad*4+r, cols = nb*16+l16)
        float p[4][4], mx[4];
        const int qrow = qt * 64 + wave * 16 + quad * 4;   // + r
        const bool diag = (kt == qt);
        for (int r = 0; r < 4; r++) mx[r] = -3.0e38f;
        for (int nb = 0; nb < 4; nb++) {
            int kk = kt * 64 + nb * 16 + l16;
            for (int r = 0; r < 4; r++) {
                float lg = sc[nb][r] * 0.125f;          // 1/sqrt(64)
                if (diag && kk > qrow + r) lg = -3.0e38f;
                p[nb][r] = lg;
                mx[r] = fmaxf(mx[r], lg);
            }
        }
        for (int off = 1; off < 16; off <<= 1)
            for (int r = 0; r < 4; r++)
                mx[r] = fmaxf(mx[r], __shfl_xor(mx[r], off, 64));
        float alpha[4], rs[4];
        for (int r = 0; r < 4; r++) {
            float mn = fmaxf(m_r[r], mx[r]);
            alpha[r] = __expf(m_r[r] - mn);
            m_r[r] = mn;
            float s = 0.f;
            for (int nb = 0; nb < 4; nb++) {
                float e = __expf(p[nb][r] - mn);
                p[nb][r] = e;
                s += e;
            }
            rs[r] = s;
        }
        for (int off = 1; off < 16; off <<= 1)
            for (int r = 0; r < 4; r++)
                rs[r] += __shfl_xor(rs[r], off, 64);
        for (int r = 0; r < 4; r++)
            l_r[r] = l_r[r] * alpha[r] + rs[r];
        for (int db = 0; db < 4; db++)
            for (int r = 0; r < 4; r++)
                acc_o[db][r] *= alpha[r];

        // P -> LDS (C-layout to A-layout round trip)
        for (int nb = 0; nb < 4; nb++)
            for (int r = 0; r < 4; r++)
                Ps[wave][(quad * 4 + r) * LD + nb * 16 + l16] = f2h(p[nb][r]);
        __syncthreads();

        // O += P V  (B from Vt rows: contiguous)
        for (int ks = 0; ks < 2; ks++) {
            half8 ap = *(const half8*)(&Ps[wave][l16 * LD + ks * 32 + quad * 8]);
            for (int db = 0; db < 4; db++) {
                half8 bv = *(const half8*)(&Vs[(db * 16 + l16) * LD + ks * 32 + quad * 8]);
                acc_o[db] = __builtin_amdgcn_mfma_f32_16x16x32_f16(ap, bv, acc_o[db], 0, 0, 0);
            }
        }
    }

    // epilogue: ctx[b][q][h*64+d] = O / l
    for (int db = 0; db < 4; db++) {
        for (int r = 0; r < 4; r++) {
            int q = qt * 64 + wave * 16 + quad * 4 + r;
            int dd = db * 16 + l16;
            float v = acc_o[db][r] / l_r[r];
            ctx[((size_t)b * S_LEN + q) * D_MODEL + h * DHEAD + dd] = f2h(v);
        }
    }
}

extern "C" void kernel_launch(void* const* d_in, const int* in_sizes, int n_in,
                              void* d_out, int out_size, void* d_ws, size_t ws_size,
                              hipStream_t stream) {
    const float* x  = (const float*)d_in[0];
    const float* Wq = (const float*)d_in[1];
    const float* Wk = (const float*)d_in[2];
    const float* Wv = (const float*)d_in[3];
    const float* Wo = (const float*)d_in[4];

    char* ws = (char*)d_ws;
    // byte offsets (all 16B aligned)
    unsigned short* Xh   = (unsigned short*)(ws + 0);            // 16 MB
    unsigned short* Wqt  = (unsigned short*)(ws + 16777216);     // 2 MB
    unsigned short* Wkt  = (unsigned short*)(ws + 18874368);     // 2 MB
    unsigned short* Wvt  = (unsigned short*)(ws + 20971520);     // 2 MB
    unsigned short* Wot  = (unsigned short*)(ws + 23068672);     // 2 MB
    unsigned short* Qh   = (unsigned short*)(ws + 25165824);     // 16 MB
    unsigned short* Kh   = (unsigned short*)(ws + 41943040);     // 16 MB
    unsigned short* Vth  = (unsigned short*)(ws + 58720256);     // 16 MB
    unsigned short* ctxh = (unsigned short*)(ws + 75497472);     // 16 MB

    const int M = BATCH * S_LEN;   // 8192
    const int N = D_MODEL;         // 1024
    const int Kdim = D_MODEL;      // 1024

    // x -> fp16
    convert_f2h_kernel<<<(M * D_MODEL / 4 + 255) / 256, 256, 0, stream>>>(x, Xh, M * D_MODEL / 4);
    // W -> Wt fp16
    dim3 tb(32, 8), tg(32, 32);
    transpose_w_kernel<<<tg, tb, 0, stream>>>(Wq, Wqt);
    transpose_w_kernel<<<tg, tb, 0, stream>>>(Wk, Wkt);
    transpose_w_kernel<<<tg, tb, 0, stream>>>(Wv, Wvt);
    transpose_w_kernel<<<tg, tb, 0, stream>>>(Wo, Wot);

    dim3 gg(N / 128, M / 128);   // (8, 64)
    gemm_nt_kernel<0><<<gg, 256, 0, stream>>>(Xh, Wqt, Qh,  M, N, Kdim);
    gemm_nt_kernel<0><<<gg, 256, 0, stream>>>(Xh, Wkt, Kh,  M, N, Kdim);
    gemm_nt_kernel<1><<<gg, 256, 0, stream>>>(Xh, Wvt, Vth, M, N, Kdim);

    attn_kernel<<<dim3(S_LEN / 64, NH, BATCH), 256, 0, stream>>>(Qh, Kh, Vth, ctxh);

    gemm_nt_kernel<2><<<gg, 256, 0, stream>>>(ctxh, Wot, d_out, M, N, Kdim);
}

// Round 2
// 294.582 us; speedup vs baseline: 1.6241x; 1.6241x over previous
//
#include <hip/hip_runtime.h>

#define S_LEN 2048
#define D_MODEL 1024
#define NH 16
#define DHEAD 64
#define BATCH 4

typedef _Float16 half8 __attribute__((ext_vector_type(8)));
typedef _Float16 half4v __attribute__((ext_vector_type(4)));
typedef float floatx4 __attribute__((ext_vector_type(4)));

__device__ __forceinline__ unsigned short f2h(float f) {
    _Float16 h = (_Float16)f;
    return __builtin_bit_cast(unsigned short, h);
}

// async global->LDS, 16B per lane; lds dest = wave-uniform base + lane*16
__device__ __forceinline__ void gload_lds16(const unsigned short* g, unsigned short* l) {
    __builtin_amdgcn_global_load_lds(
        (const __attribute__((address_space(1))) void*)g,
        (__attribute__((address_space(3))) void*)l,
        16, 0, 0);
}

// ---------------- conversion: fp32 -> fp16 bits ---------------------------------
__global__ __launch_bounds__(256) void convert_f2h_kernel(const float* __restrict__ in,
                                                          unsigned short* __restrict__ out,
                                                          int n4) {
    int i = blockIdx.x * 256 + threadIdx.x;
    if (i < n4) {
        float4 v = ((const float4*)in)[i];
        ushort4 o;
        o.x = f2h(v.x); o.y = f2h(v.y); o.z = f2h(v.z); o.w = f2h(v.w);
        ((ushort4*)out)[i] = o;
    }
}

// ---------------- 4 x (W [K][N] fp32 -> Wt [N][K] fp16) fused -------------------
__global__ __launch_bounds__(256) void transpose_w_kernel(const float* __restrict__ W0,
                                                          const float* __restrict__ W1,
                                                          const float* __restrict__ W2,
                                                          const float* __restrict__ W3,
                                                          unsigned short* __restrict__ T0,
                                                          unsigned short* __restrict__ T1,
                                                          unsigned short* __restrict__ T2,
                                                          unsigned short* __restrict__ T3) {
    const float* W = blockIdx.z == 0 ? W0 : blockIdx.z == 1 ? W1 : blockIdx.z == 2 ? W2 : W3;
    unsigned short* Wt = blockIdx.z == 0 ? T0 : blockIdx.z == 1 ? T1 : blockIdx.z == 2 ? T2 : T3;
    __shared__ float tile[32][33];
    int x = threadIdx.x;   // 0..31
    int y = threadIdx.y;   // 0..7
    int k0 = blockIdx.y * 32;
    int n0 = blockIdx.x * 32;
    for (int i = 0; i < 4; i++)
        tile[y + 8 * i][x] = W[(size_t)(k0 + y + 8 * i) * D_MODEL + n0 + x];
    __syncthreads();
    for (int i = 0; i < 4; i++)
        Wt[(size_t)(n0 + y + 8 * i) * D_MODEL + k0 + x] = f2h(tile[x][y + 8 * i]);
}

// ---------------- NT GEMM body: C[M][N] = A[M][K] * Bt[N][K]^T ------------------
// mode 0: fp16 out to Q/K layout [b][h][s][dh]; mode 1: fp16 to V^T [b][h][dh][s];
// mode 2: fp32 to [M][N]. LDS unpadded (32 halfs/row), XOR chunk swizzle.
__device__ __forceinline__ void gemm_body(const unsigned short* __restrict__ A,
                                          const unsigned short* __restrict__ Bt,
                                          void* __restrict__ Cout,
                                          int M, int N, int K, int mode,
                                          int bx, int by,
                                          unsigned short* As, unsigned short* Bs) {
    const int tid  = threadIdx.x;
    const int wave = tid >> 6;
    const int lane = tid & 63;
    const int quad = lane >> 4;
    const int l16  = lane & 15;
    const int wm = (wave >> 1) * 64;
    const int wn = (wave & 1) * 64;
    const int tm = by * 128;
    const int tn = bx * 128;

    // staging geometry (constant across k0)
    const int ci0 = wave * 128 + lane;        // j=0 chunk id
    const int row0 = ci0 >> 2, s0 = ci0 & 3;
    const int gc0 = s0 ^ ((row0 >> 1) & 3);
    const int ci1 = ci0 + 64;
    const int row1 = ci1 >> 2, s1 = ci1 & 3;
    const int gc1 = s1 ^ ((row1 >> 1) & 3);

    floatx4 acc[4][4] = {};

    for (int k0 = 0; k0 < K; k0 += 32) {
        __syncthreads();
        gload_lds16(A  + (size_t)(tm + row0) * K + k0 + gc0 * 8, &As[(wave * 2 + 0) * 512]);
        gload_lds16(A  + (size_t)(tm + row1) * K + k0 + gc1 * 8, &As[(wave * 2 + 1) * 512]);
        gload_lds16(Bt + (size_t)(tn + row0) * K + k0 + gc0 * 8, &Bs[(wave * 2 + 0) * 512]);
        gload_lds16(Bt + (size_t)(tn + row1) * K + k0 + gc1 * 8, &Bs[(wave * 2 + 1) * 512]);
        __syncthreads();

        half8 af[4], bf[4];
#pragma unroll
        for (int mi = 0; mi < 4; mi++) {
            int row = wm + mi * 16 + l16;
            af[mi] = *(const half8*)(&As[row * 32 + (quad ^ ((row >> 1) & 3)) * 8]);
        }
#pragma unroll
        for (int ni = 0; ni < 4; ni++) {
            int row = wn + ni * 16 + l16;
            bf[ni] = *(const half8*)(&Bs[row * 32 + (quad ^ ((row >> 1) & 3)) * 8]);
        }
#pragma unroll
        for (int mi = 0; mi < 4; mi++)
#pragma unroll
            for (int ni = 0; ni < 4; ni++)
                acc[mi][ni] = __builtin_amdgcn_mfma_f32_16x16x32_f16(af[mi], bf[ni], acc[mi][ni], 0, 0, 0);
    }

#pragma unroll
    for (int mi = 0; mi < 4; mi++) {
#pragma unroll
        for (int ni = 0; ni < 4; ni++) {
#pragma unroll
            for (int r = 0; r < 4; r++) {
                int row = tm + wm + mi * 16 + quad * 4 + r;   // m
                int col = tn + wn + ni * 16 + l16;            // n
                float v = acc[mi][ni][r];
                if (mode == 2) {
                    ((float*)Cout)[(size_t)row * N + col] = v;
                } else {
                    int b = row >> 11, s = row & 2047;
                    int h = col >> 6,  dh = col & 63;
                    size_t idx;
                    if (mode == 0) idx = ((size_t)(b * NH + h) * S_LEN + s) * DHEAD + dh;
                    else           idx = ((size_t)(b * NH + h) * DHEAD + dh) * S_LEN + s;
                    ((unsigned short*)Cout)[idx] = f2h(v);
                }
            }
        }
    }
}

// fused QKV projection: z=0 Q (mode0), z=1 K (mode0), z=2 V (mode1)
__global__ __launch_bounds__(256) void qkv_gemm_kernel(const unsigned short* __restrict__ A,
                                                       const unsigned short* __restrict__ Wq,
                                                       const unsigned short* __restrict__ Wk,
                                                       const unsigned short* __restrict__ Wv,
                                                       unsigned short* __restrict__ Qo,
                                                       unsigned short* __restrict__ Ko,
                                                       unsigned short* __restrict__ Vo) {
    __shared__ unsigned short As[128 * 32];
    __shared__ unsigned short Bs[128 * 32];
    const int z = blockIdx.z;
    const unsigned short* Bt = z == 0 ? Wq : z == 1 ? Wk : Wv;
    void* out = z == 0 ? (void*)Qo : z == 1 ? (void*)Ko : (void*)Vo;
    gemm_body(A, Bt, out, BATCH * S_LEN, D_MODEL, D_MODEL, z == 2 ? 1 : 0,
              blockIdx.x, blockIdx.y, As, Bs);
}

__global__ __launch_bounds__(256) void out_gemm_kernel(const unsigned short* __restrict__ A,
                                                       const unsigned short* __restrict__ Bt,
                                                       float* __restrict__ C) {
    __shared__ unsigned short As[128 * 32];
    __shared__ unsigned short Bs[128 * 32];
    gemm_body(A, Bt, C, BATCH * S_LEN, D_MODEL, D_MODEL, 2, blockIdx.x, blockIdx.y, As, Bs);
}

// ---------------- Flash attention (causal), balanced two-tile blocks ------------
// Q,K: [b][h][s][dh] fp16 ; Vt: [b][h][dh][s] fp16 ; ctx: [b][s][h*dh] fp16
// Block handles q-tiles bx and 31-bx (64 rows each) -> uniform 33 iterations.
// S^T layout: lane owns q = l16 (16 in-lane kk values), reductions = tree + 2 shfl.
__global__ __launch_bounds__(256) void attn_kernel(const unsigned short* __restrict__ Q,
                                                   const unsigned short* __restrict__ K,
                                                   const unsigned short* __restrict__ Vt,
                                                   unsigned short* __restrict__ ctx) {
    __shared__ unsigned short Ks[64 * 64];     // [kk][dh], XOR-swizzled chunks
    __shared__ unsigned short Vs[64 * 64];     // [dh][kk], XOR-swizzled chunks
    __shared__ unsigned short Ps[4][16 * 72];  // per-wave P [q][kk], LD=72 halfs
    const int tid  = threadIdx.x;
    const int wave = tid >> 6;
    const int lane = tid & 63;
    const int quad = lane >> 4;
    const int l16  = lane & 15;
    const int bx = blockIdx.x;
    const int h  = blockIdx.y;
    const int b  = blockIdx.z;
    const size_t head = (size_t)(b * NH + h) * (S_LEN * DHEAD);

    // staging geometry: wave loads chunks [wave*128, wave*128+127] (rows of 8 chunks)
    const int ci0 = wave * 128 + lane;
    const int row0 = ci0 >> 3, gc0 = (ci0 & 7) ^ (row0 & 7);
    const int ci1 = ci0 + 64;
    const int row1 = ci1 >> 3, gc1 = (ci1 & 7) ^ (row1 & 7);

    for (int phase = 0; phase < 2; phase++) {
        const int qt = phase ? (31 - bx) : bx;
        const int qg = qt * 64 + wave * 16 + l16;   // this lane's softmax q row

        // Q B-fragments, straight from global (layout == A-frag of Q)
        half8 qf0 = *(const half8*)(Q + head + (size_t)qg * DHEAD + quad * 8);
        half8 qf1 = *(const half8*)(Q + head + (size_t)qg * DHEAD + 32 + quad * 8);

        floatx4 acc[4] = {};
        float m_s = -3.0e38f, l_s = 0.f;

        for (int kt = 0; kt <= qt; kt++) {
            __syncthreads();   // prior-iter LDS readers done
            gload_lds16(K  + head + (size_t)(kt * 64 + row0) * DHEAD + gc0 * 8, &Ks[(wave * 2 + 0) * 512]);
            gload_lds16(K  + head + (size_t)(kt * 64 + row1) * DHEAD + gc1 * 8, &Ks[(wave * 2 + 1) * 512]);
            gload_lds16(Vt + head + (size_t)row0 * S_LEN + kt * 64 + gc0 * 8,   &Vs[(wave * 2 + 0) * 512]);
            gload_lds16(Vt + head + (size_t)row1 * S_LEN + kt * 64 + gc1 * 8,   &Vs[(wave * 2 + 1) * 512]);
            __syncthreads();   // staging visible (barrier drains vmcnt)

            // S^T = K Q^T : C col = q = l16, row = kk = mk*16 + quad*4 + r
            floatx4 sc[4] = {};
#pragma unroll
            for (int ks = 0; ks < 2; ks++) {
#pragma unroll
                for (int mk = 0; mk < 4; mk++) {
                    int row = mk * 16 + l16;
                    half8 ak = *(const half8*)(&Ks[row * 64 + (((ks << 2) + quad) ^ (row & 7)) * 8]);
                    sc[mk] = __builtin_amdgcn_mfma_f32_16x16x32_f16(ak, ks ? qf1 : qf0, sc[mk], 0, 0, 0);
                }
            }

            // online softmax over this lane's 16 kk values (q = l16)
            const bool diag = (kt == qt);
            float pv[4][4];
            float mx = -3.0e38f;
#pragma unroll
            for (int mk = 0; mk < 4; mk++)
#pragma unroll
                for (int r = 0; r < 4; r++) {
                    float lg = sc[mk][r] * 0.125f;   // 1/sqrt(64)
                    if (diag) {
                        int kk = kt * 64 + mk * 16 + quad * 4 + r;
                        if (kk > qg) lg = -3.0e38f;
                    }
                    pv[mk][r] = lg;
                    mx = fmaxf(mx, lg);
                }
            mx = fmaxf(mx, __shfl_xor(mx, 16, 64));
            mx = fmaxf(mx, __shfl_xor(mx, 32, 64));
            float mn = fmaxf(m_s, mx);
            float alpha = __expf(m_s - mn);
            m_s = mn;
            float rs = 0.f;
#pragma unroll
            for (int mk = 0; mk < 4; mk++)
#pragma unroll
                for (int r = 0; r < 4; r++) {
                    float e = __expf(pv[mk][r] - mn);
                    pv[mk][r] = e;
                    rs += e;
                }
            rs += __shfl_xor(rs, 16, 64);
            rs += __shfl_xor(rs, 32, 64);
            l_s = l_s * alpha + rs;

            // rescale O (O rows live at q = quad*4+r -> fetch alpha from lane quad*4+r)
            float ao[4];
#pragma unroll
            for (int r = 0; r < 4; r++) ao[r] = __shfl(alpha, quad * 4 + r, 64);
#pragma unroll
            for (int db = 0; db < 4; db++)
#pragma unroll
                for (int r = 0; r < 4; r++) acc[db][r] *= ao[r];

            // P -> per-wave LDS rows [q=l16][kk] (same-wave DS ordering: no barrier)
#pragma unroll
            for (int mk = 0; mk < 4; mk++) {
                half4v ph;
#pragma unroll
                for (int r = 0; r < 4; r++) ph[r] = (_Float16)pv[mk][r];
                *(half4v*)(&Ps[wave][l16 * 72 + mk * 16 + quad * 4]) = ph;
            }

            // O += P V : A = P[q][kk] (own-wave Ps), B = Vt rows
#pragma unroll
            for (int ks = 0; ks < 2; ks++) {
                half8 ap = *(const half8*)(&Ps[wave][l16 * 72 + ks * 32 + quad * 8]);
#pragma unroll
                for (int db = 0; db < 4; db++) {
                    int row = db * 16 + l16;
                    half8 bv = *(const half8*)(&Vs[row * 64 + (((ks << 2) + quad) ^ (row & 7)) * 8]);
                    acc[db] = __builtin_amdgcn_mfma_f32_16x16x32_f16(ap, bv, acc[db], 0, 0, 0);
                }
            }
        }

        // epilogue: O row q = quad*4+r; fetch l from lane quad*4+r
        float lo[4];
#pragma unroll
        for (int r = 0; r < 4; r++) lo[r] = __shfl(l_s, quad * 4 + r, 64);
#pragma unroll
        for (int db = 0; db < 4; db++)
#pragma unroll
            for (int r = 0; r < 4; r++) {
                int q  = qt * 64 + wave * 16 + quad * 4 + r;
                int dd = db * 16 + l16;
                ctx[((size_t)b * S_LEN + q) * D_MODEL + h * DHEAD + dd] = f2h(acc[db][r] / lo[r]);
            }
    }
}

extern "C" void kernel_launch(void* const* d_in, const int* in_sizes, int n_in,
                              void* d_out, int out_size, void* d_ws, size_t ws_size,
                              hipStream_t stream) {
    const float* x  = (const float*)d_in[0];
    const float* Wq = (const float*)d_in[1];
    const float* Wk = (const float*)d_in[2];
    const float* Wv = (const float*)d_in[3];
    const float* Wo = (const float*)d_in[4];

    char* ws = (char*)d_ws;
    unsigned short* Xh   = (unsigned short*)(ws + 0);            // 16 MB
    unsigned short* Wqt  = (unsigned short*)(ws + 16777216);     // 2 MB
    unsigned short* Wkt  = (unsigned short*)(ws + 18874368);     // 2 MB
    unsigned short* Wvt  = (unsigned short*)(ws + 20971520);     // 2 MB
    unsigned short* Wot  = (unsigned short*)(ws + 23068672);     // 2 MB
    unsigned short* Qh   = (unsigned short*)(ws + 25165824);     // 16 MB
    unsigned short* Kh   = (unsigned short*)(ws + 41943040);     // 16 MB
    unsigned short* Vth  = (unsigned short*)(ws + 58720256);     // 16 MB
    unsigned short* ctxh = (unsigned short*)(ws + 75497472);     // 16 MB

    const int M = BATCH * S_LEN;   // 8192

    convert_f2h_kernel<<<(M * D_MODEL / 4 + 255) / 256, 256, 0, stream>>>(x, Xh, M * D_MODEL / 4);
    transpose_w_kernel<<<dim3(32, 32, 4), dim3(32, 8), 0, stream>>>(Wq, Wk, Wv, Wo, Wqt, Wkt, Wvt, Wot);

    qkv_gemm_kernel<<<dim3(8, 64, 3), 256, 0, stream>>>(Xh, Wqt, Wkt, Wvt, Qh, Kh, Vth);

    attn_kernel<<<dim3(16, NH, BATCH), 256, 0, stream>>>(Qh, Kh, Vth, ctxh);

    out_gemm_kernel<<<dim3(8, 64), 256, 0, stream>>>(ctxh, Wot, (float*)d_out);
}

// Round 4
// 285.544 us; speedup vs baseline: 1.6755x; 1.0317x over previous
//
#include <hip/hip_runtime.h>

#define S_LEN 2048
#define D_MODEL 1024
#define NH 16
#define DHEAD 64
#define BATCH 4

typedef _Float16 half8 __attribute__((ext_vector_type(8)));
typedef _Float16 half4v __attribute__((ext_vector_type(4)));
typedef float floatx4 __attribute__((ext_vector_type(4)));

#define EXP2SCALE 0.1803368801111244f   // 0.125 * log2(e)

__device__ __forceinline__ unsigned short f2h(float f) {
    _Float16 h = (_Float16)f;
    return __builtin_bit_cast(unsigned short, h);
}

// async global->LDS, 16B per lane; lds dest = wave-uniform base + lane*16
__device__ __forceinline__ void gload_lds16(const unsigned short* g, unsigned short* l) {
    __builtin_amdgcn_global_load_lds(
        (const __attribute__((address_space(1))) void*)g,
        (__attribute__((address_space(3))) void*)l,
        16, 0, 0);
}

// ---------------- conversion: fp32 -> fp16 bits ---------------------------------
__global__ __launch_bounds__(256) void convert_f2h_kernel(const float* __restrict__ in,
                                                          unsigned short* __restrict__ out,
                                                          int n4) {
    int i = blockIdx.x * 256 + threadIdx.x;
    if (i < n4) {
        float4 v = ((const float4*)in)[i];
        ushort4 o;
        o.x = f2h(v.x); o.y = f2h(v.y); o.z = f2h(v.z); o.w = f2h(v.w);
        ((ushort4*)out)[i] = o;
    }
}

// ---------------- 4 x (W [K][N] fp32 -> Wt [N][K] fp16) fused -------------------
__global__ __launch_bounds__(256) void transpose_w_kernel(const float* __restrict__ W0,
                                                          const float* __restrict__ W1,
                                                          const float* __restrict__ W2,
                                                          const float* __restrict__ W3,
                                                          unsigned short* __restrict__ T0,
                                                          unsigned short* __restrict__ T1,
                                                          unsigned short* __restrict__ T2,
                                                          unsigned short* __restrict__ T3) {
    const float* W = blockIdx.z == 0 ? W0 : blockIdx.z == 1 ? W1 : blockIdx.z == 2 ? W2 : W3;
    unsigned short* Wt = blockIdx.z == 0 ? T0 : blockIdx.z == 1 ? T1 : blockIdx.z == 2 ? T2 : T3;
    __shared__ float tile[32][33];
    int x = threadIdx.x;
    int y = threadIdx.y;
    int k0 = blockIdx.y * 32;
    int n0 = blockIdx.x * 32;
    for (int i = 0; i < 4; i++)
        tile[y + 8 * i][x] = W[(size_t)(k0 + y + 8 * i) * D_MODEL + n0 + x];
    __syncthreads();
    for (int i = 0; i < 4; i++)
        Wt[(size_t)(n0 + y + 8 * i) * D_MODEL + k0 + x] = f2h(tile[x][y + 8 * i]);
}

// ---------------- NT GEMM body: C[M][N] = A[M][K] * Bt[N][K]^T ------------------
// MODE 0: fp16 -> Q/K layout [b][h][s][dh], LDS-bounce coalesced stores
// MODE 1: fp16 -> V^T layout [b][h][dh][s], LDS-bounce (transposed) stores
// MODE 2: fp32 -> [M][N] direct stores
// smem: 32KB (16384 halfs). K-loop uses first 16KB as As|Bs; epilogue reuses all.
template<int MODE>
__device__ __forceinline__ void gemm_body(const unsigned short* __restrict__ A,
                                          const unsigned short* __restrict__ Bt,
                                          void* __restrict__ Cout,
                                          int M, int N, int K,
                                          int bx, int by,
                                          unsigned short* smem) {
    unsigned short* As = smem;             // 128*32 halfs
    unsigned short* Bs = smem + 4096;      // 128*32 halfs
    const int tid  = threadIdx.x;
    const int wave = tid >> 6;
    const int lane = tid & 63;
    const int quad = lane >> 4;
    const int l16  = lane & 15;
    const int wm = (wave >> 1) * 64;
    const int wn = (wave & 1) * 64;
    const int tm = by * 128;
    const int tn = bx * 128;

    const int ci0 = wave * 128 + lane;
    const int row0 = ci0 >> 2, s0 = ci0 & 3;
    const int gc0 = s0 ^ ((row0 >> 1) & 3);
    const int ci1 = ci0 + 64;
    const int row1 = ci1 >> 2, s1 = ci1 & 3;
    const int gc1 = s1 ^ ((row1 >> 1) & 3);

    floatx4 acc[4][4] = {};

    for (int k0 = 0; k0 < K; k0 += 32) {
        __syncthreads();
        gload_lds16(A  + (size_t)(tm + row0) * K + k0 + gc0 * 8, &As[(wave * 2 + 0) * 512]);
        gload_lds16(A  + (size_t)(tm + row1) * K + k0 + gc1 * 8, &As[(wave * 2 + 1) * 512]);
        gload_lds16(Bt + (size_t)(tn + row0) * K + k0 + gc0 * 8, &Bs[(wave * 2 + 0) * 512]);
        gload_lds16(Bt + (size_t)(tn + row1) * K + k0 + gc1 * 8, &Bs[(wave * 2 + 1) * 512]);
        __syncthreads();

        half8 af[4], bf[4];
#pragma unroll
        for (int mi = 0; mi < 4; mi++) {
            int row = wm + mi * 16 + l16;
            af[mi] = *(const half8*)(&As[row * 32 + (quad ^ ((row >> 1) & 3)) * 8]);
        }
#pragma unroll
        for (int ni = 0; ni < 4; ni++) {
            int row = wn + ni * 16 + l16;
            bf[ni] = *(const half8*)(&Bs[row * 32 + (quad ^ ((row >> 1) & 3)) * 8]);
        }
#pragma unroll
        for (int mi = 0; mi < 4; mi++)
#pragma unroll
            for (int ni = 0; ni < 4; ni++)
                acc[mi][ni] = __builtin_amdgcn_mfma_f32_16x16x32_f16(af[mi], bf[ni], acc[mi][ni], 0, 0, 0);
    }

    if (MODE == 2) {
#pragma unroll
        for (int mi = 0; mi < 4; mi++)
#pragma unroll
            for (int ni = 0; ni < 4; ni++)
#pragma unroll
                for (int r = 0; r < 4; r++) {
                    int row = tm + wm + mi * 16 + quad * 4 + r;
                    int col = tn + wn + ni * 16 + l16;
                    ((float*)Cout)[(size_t)row * N + col] = acc[mi][ni][r];
                }
        return;
    }

    // ---- LDS bounce: acc tile (128x128 fp16 = 32KB) -> coalesced stores --------
    // chunk = 16 elements (32B); swizzle on chunk index; 16B vectors = half-chunks.
    __syncthreads();   // all waves done reading As/Bs
    if (MODE == 0) {
        // write phys = row*128 + ((cc ^ ((row>>2)&7))<<4) + (col&15), cc = col>>4
#pragma unroll
        for (int mi = 0; mi < 4; mi++)
#pragma unroll
            for (int ni = 0; ni < 4; ni++) {
                int col = wn + ni * 16 + l16;
                int cc  = col >> 4;
                int cil = col & 15;
#pragma unroll
                for (int r = 0; r < 4; r++) {
                    int row = wm + mi * 16 + quad * 4 + r;
                    smem[row * 128 + ((cc ^ ((row >> 2) & 7)) << 4) + cil] = f2h(acc[mi][ni][r]);
                }
            }
        __syncthreads();
        // read 2048 x 16B vectors, store coalesced to [b][h][s][dh]
        unsigned short* O = (unsigned short*)Cout;
#pragma unroll
        for (int j = 0; j < 8; j++) {
            int vid = tid + j * 256;          // 0..2047
            int row = vid >> 4, vv = vid & 15;
            int cc = vv >> 1, hf = vv & 1;
            uint4 v = *(const uint4*)(&smem[row * 128 + ((cc ^ ((row >> 2) & 7)) << 4) + hf * 8]);
            int grow = tm + row;
            int b = grow >> 11, s = grow & 2047;
            int n = tn + vv * 8;
            int h = n >> 6, dh = n & 63;
            *(uint4*)(O + (((size_t)(b * NH + h) * S_LEN + s) * DHEAD + dh)) = v;
        }
    } else {
        // write phys = col*128 + (((row>>4) ^ ((col>>2)&7))<<4) + (row&15)
#pragma unroll
        for (int mi = 0; mi < 4; mi++)
#pragma unroll
            for (int ni = 0; ni < 4; ni++) {
                int col = wn + ni * 16 + l16;
                int sw  = (col >> 2) & 7;
#pragma unroll
                for (int r = 0; r < 4; r++) {
                    int row = wm + mi * 16 + quad * 4 + r;
                    smem[col * 128 + (((row >> 4) ^ sw) << 4) + (row & 15)] = f2h(acc[mi][ni][r]);
                }
            }
        __syncthreads();
        // read 2048 x 16B vectors (row-major in s), store coalesced to [b][h][dh][s]
        unsigned short* O = (unsigned short*)Cout;
        int b = tm >> 11;
        int sbase = tm & 2047;
#pragma unroll
        for (int j = 0; j < 8; j++) {
            int vid = tid + j * 256;
            int colr = vid >> 4, vv = vid & 15;   // colr = n index within tile
            int rc = vv >> 1, hf = vv & 1;
            uint4 v = *(const uint4*)(&smem[colr * 128 + ((rc ^ ((colr >> 2) & 7)) << 4) + hf * 8]);
            int n = tn + colr;
            int h = n >> 6, dh = n & 63;
            *(uint4*)(O + (((size_t)(b * NH + h) * DHEAD + dh) * S_LEN + sbase + vv * 8)) = v;
        }
    }
}

// fused QKV projection: z=0 Q (mode0), z=1 K (mode0), z=2 V (mode1)
__global__ __launch_bounds__(256) void qkv_gemm_kernel(const unsigned short* __restrict__ A,
                                                       const unsigned short* __restrict__ Wq,
                                                       const unsigned short* __restrict__ Wk,
                                                       const unsigned short* __restrict__ Wv,
                                                       unsigned short* __restrict__ Qo,
                                                       unsigned short* __restrict__ Ko,
                                                       unsigned short* __restrict__ Vo) {
    __shared__ unsigned short smem[128 * 128];
    const int z = blockIdx.z;
    if (z == 2)
        gemm_body<1>(A, Wv, Vo, BATCH * S_LEN, D_MODEL, D_MODEL, blockIdx.x, blockIdx.y, smem);
    else
        gemm_body<0>(A, z == 0 ? Wq : Wk, z == 0 ? Qo : Ko,
                     BATCH * S_LEN, D_MODEL, D_MODEL, blockIdx.x, blockIdx.y, smem);
}

__global__ __launch_bounds__(256) void out_gemm_kernel(const unsigned short* __restrict__ A,
                                                       const unsigned short* __restrict__ Bt,
                                                       float* __restrict__ C) {
    __shared__ unsigned short smem[128 * 128];
    gemm_body<2>(A, Bt, C, BATCH * S_LEN, D_MODEL, D_MODEL, blockIdx.x, blockIdx.y, smem);
}

// ---------------- Flash attention (causal), 128 q-rows per block ----------------
// Q,K: [b][h][s][dh] fp16 ; Vt: [b][h][dh][s] fp16 ; ctx: [b][s][h*dh] fp16
// 512 threads / 8 waves; wave w owns q rows t*128 + w*16 .. +15.
// Block handles q-tiles t=bx and t=15-bx -> uniform 36 K-iterations.
__global__ __launch_bounds__(512, 4) void attn_kernel(const unsigned short* __restrict__ Q,
                                                      const unsigned short* __restrict__ K,
                                                      const unsigned short* __restrict__ Vt,
                                                      unsigned short* __restrict__ ctx) {
    __shared__ unsigned short Ks[64 * 64];     // [kk][dh], XOR-swizzled chunks
    __shared__ unsigned short Vs[64 * 64];     // [dh][kk], XOR-swizzled chunks
    __shared__ unsigned short Ps[8][16 * 72];  // per-wave P [q][kk]
    const int tid  = threadIdx.x;
    const int wave = tid >> 6;
    const int lane = tid & 63;
    const int quad = lane >> 4;
    const int l16  = lane & 15;
    const int bx = blockIdx.x;   // 0..7 (pair index)
    const int h  = blockIdx.y;
    const int b  = blockIdx.z;
    const size_t head = (size_t)(b * NH + h) * (S_LEN * DHEAD);

    // staging: 512 lanes x 16B = one 64x64 fp16 tile per array
    const int ci  = wave * 64 + lane;
    const int srow = ci >> 3;
    const int sgc  = (ci & 7) ^ (srow & 7);

    for (int phase = 0; phase < 2; phase++) {
        const int t  = phase ? (15 - bx) : bx;
        const int qg = t * 128 + wave * 16 + l16;   // this lane's softmax q row
        const int dk = 2 * t + (wave >> 2);         // wave's diagonal k-tile

        half8 qf0 = *(const half8*)(Q + head + (size_t)qg * DHEAD + quad * 8);
        half8 qf1 = *(const half8*)(Q + head + (size_t)qg * DHEAD + 32 + quad * 8);

        floatx4 acc[4] = {};
        float m_s = -3.0e38f, l_s = 0.f;

        for (int kt = 0; kt <= 2 * t + 1; kt++) {
            __syncthreads();   // prior-iter LDS readers done
            gload_lds16(K  + head + (size_t)(kt * 64 + srow) * DHEAD + sgc * 8, &Ks[wave * 512]);
            gload_lds16(Vt + head + (size_t)srow * S_LEN + kt * 64 + sgc * 8,   &Vs[wave * 512]);
            __syncthreads();   // staging visible

            if (kt > dk) continue;   // above diagonal: no work (barriers stay uniform)

            // S^T = K Q^T : C col = q = l16, row = kk = mk*16 + quad*4 + r
            floatx4 sc[4] = {};
#pragma unroll
            for (int ks = 0; ks < 2; ks++) {
#pragma unroll
                for (int mk = 0; mk < 4; mk++) {
                    int row = mk * 16 + l16;
                    half8 ak = *(const half8*)(&Ks[row * 64 + (((ks << 2) + quad) ^ (row & 7)) * 8]);
                    sc[mk] = __builtin_amdgcn_mfma_f32_16x16x32_f16(ak, ks ? qf1 : qf0, sc[mk], 0, 0, 0);
                }
            }

            // online softmax in exp2 domain over this lane's 16 kk values
            const bool diag = (kt == dk);
            float pv[4][4];
            float mx = -3.0e38f;
#pragma unroll
            for (int mk = 0; mk < 4; mk++)
#pragma unroll
                for (int r = 0; r < 4; r++) {
                    float lg = sc[mk][r] * EXP2SCALE;
                    if (diag) {
                        int kk = kt * 64 + mk * 16 + quad * 4 + r;
                        if (kk > qg) lg = -3.0e38f;
                    }
                    pv[mk][r] = lg;
                    mx = fmaxf(mx, lg);
                }
            mx = fmaxf(mx, __shfl_xor(mx, 16, 64));
            mx = fmaxf(mx, __shfl_xor(mx, 32, 64));
            float mn = fmaxf(m_s, mx);
            float alpha = exp2f(m_s - mn);
            m_s = mn;
            float rs = 0.f;
#pragma unroll
            for (int mk = 0; mk < 4; mk++)
#pragma unroll
                for (int r = 0; r < 4; r++) {
                    float e = exp2f(pv[mk][r] - mn);
                    pv[mk][r] = e;
                    rs += e;
                }
            rs += __shfl_xor(rs, 16, 64);
            rs += __shfl_xor(rs, 32, 64);
            l_s = l_s * alpha + rs;

            // rescale O (O rows at q = quad*4+r -> alpha from lane quad*4+r)
            float ao[4];
#pragma unroll
            for (int r = 0; r < 4; r++) ao[r] = __shfl(alpha, quad * 4 + r, 64);
#pragma unroll
            for (int db = 0; db < 4; db++)
#pragma unroll
                for (int r = 0; r < 4; r++) acc[db][r] *= ao[r];

            // P -> per-wave LDS rows [q=l16][kk] (same-wave DS ordering: no barrier)
#pragma unroll
            for (int mk = 0; mk < 4; mk++) {
                half4v ph;
#pragma unroll
                for (int r = 0; r < 4; r++) ph[r] = (_Float16)pv[mk][r];
                *(half4v*)(&Ps[wave][l16 * 72 + mk * 16 + quad * 4]) = ph;
            }

            // O += P V : A = P[q][kk] (own-wave Ps), B = Vt rows
#pragma unroll
            for (int ks = 0; ks < 2; ks++) {
                half8 ap = *(const half8*)(&Ps[wave][l16 * 72 + ks * 32 + quad * 8]);
#pragma unroll
                for (int db = 0; db < 4; db++) {
                    int row = db * 16 + l16;
                    half8 bv = *(const half8*)(&Vs[row * 64 + (((ks << 2) + quad) ^ (row & 7)) * 8]);
                    acc[db] = __builtin_amdgcn_mfma_f32_16x16x32_f16(ap, bv, acc[db], 0, 0, 0);
                }
            }
        }

        // epilogue: O row q = quad*4+r; fetch l from lane quad*4+r
        float lo[4];
#pragma unroll
        for (int r = 0; r < 4; r++) lo[r] = __shfl(l_s, quad * 4 + r, 64);
#pragma unroll
        for (int db = 0; db < 4; db++)
#pragma unroll
            for (int r = 0; r < 4; r++) {
                int q  = t * 128 + wave * 16 + quad * 4 + r;
                int dd = db * 16 + l16;
                ctx[((size_t)b * S_LEN + q) * D_MODEL + h * DHEAD + dd] = f2h(acc[db][r] / lo[r]);
            }
    }
}

extern "C" void kernel_launch(void* const* d_in, const int* in_sizes, int n_in,
                              void* d_out, int out_size, void* d_ws, size_t ws_size,
                              hipStream_t stream) {
    const float* x  = (const float*)d_in[0];
    const float* Wq = (const float*)d_in[1];
    const float* Wk = (const float*)d_in[2];
    const float* Wv = (const float*)d_in[3];
    const float* Wo = (const float*)d_in[4];

    char* ws = (char*)d_ws;
    unsigned short* Xh   = (unsigned short*)(ws + 0);            // 16 MB
    unsigned short* Wqt  = (unsigned short*)(ws + 16777216);     // 2 MB
    unsigned short* Wkt  = (unsigned short*)(ws + 18874368);     // 2 MB
    unsigned short* Wvt  = (unsigned short*)(ws + 20971520);     // 2 MB
    unsigned short* Wot  = (unsigned short*)(ws + 23068672);     // 2 MB
    unsigned short* Qh   = (unsigned short*)(ws + 25165824);     // 16 MB
    unsigned short* Kh   = (unsigned short*)(ws + 41943040);     // 16 MB
    unsigned short* Vth  = (unsigned short*)(ws + 58720256);     // 16 MB
    unsigned short* ctxh = (unsigned short*)(ws + 75497472);     // 16 MB

    const int M = BATCH * S_LEN;   // 8192

    convert_f2h_kernel<<<(M * D_MODEL / 4 + 255) / 256, 256, 0, stream>>>(x, Xh, M * D_MODEL / 4);
    transpose_w_kernel<<<dim3(32, 32, 4), dim3(32, 8), 0, stream>>>(Wq, Wk, Wv, Wo, Wqt, Wkt, Wvt, Wot);

    qkv_gemm_kernel<<<dim3(8, 64, 3), 256, 0, stream>>>(Xh, Wqt, Wkt, Wvt, Qh, Kh, Vth);

    attn_kernel<<<dim3(8, NH, BATCH), 512, 0, stream>>>(Qh, Kh, Vth, ctxh);

    out_gemm_kernel<<<dim3(8, 64), 256, 0, stream>>>(ctxh, Wot, (float*)d_out);
}